// Round 1
// baseline (1681.952 us; speedup 1.0000x reference)
//
#include <hip/hip_runtime.h>
#include <hip/hip_bf16.h>

#define BATCH   4096
#define NIN     2048
#define NOUT    2048
#define GS      8

typedef __attribute__((ext_vector_type(8))) short  bf16x8;   // MFMA A/B frag (4 VGPR)
typedef __attribute__((ext_vector_type(4))) float  f32x4;    // MFMA C/D frag

// round-to-nearest-even f32 -> bf16 (values here are finite, no NaN concern)
__device__ __forceinline__ short f2bf(float f) {
    unsigned u = __builtin_bit_cast(unsigned, f);
    u += 0x7fffu + ((u >> 16) & 1u);
    return (short)(u >> 16);
}

// KAN layer as implicit GEMM:  A[b, i*8+k] = basis(x[b,i], k)   (computed in-register)
//                              B[i*8+k, j] = coef[i, j, k]      (32B-contiguous per lane)
// No LDS, no barriers, no workspace. 128x128 tile / block of 4 waves (2x2 of 64x64).
__global__ __launch_bounds__(256, 2)
void kan_kernel(const float* __restrict__ x,
                const float* __restrict__ coef,
                const float* __restrict__ grid,
                float* __restrict__ out)
{
    const int tid  = threadIdx.x;
    const int wave = tid >> 6;
    const int lane = tid & 63;
    const int l15  = lane & 15;
    const int quad = lane >> 4;

    const int wm = wave & 1;
    const int wn = wave >> 1;
    const int m_base = blockIdx.x * 128 + wm * 64;   // + ms*16 + l15
    const int n_base = blockIdx.y * 128 + wn * 64;   // + ns*16 + l15

    float g[GS];
#pragma unroll
    for (int k = 0; k < GS; ++k) g[k] = grid[k];

    const float KE = -7.2134752044448170f;   // -5 * log2(e):  exp(-5 t^2) = exp2(KE * t^2)

    f32x4 acc[4][4];
#pragma unroll
    for (int a = 0; a < 4; ++a)
#pragma unroll
        for (int b = 0; b < 4; ++b)
            acc[a][b] = (f32x4){0.f, 0.f, 0.f, 0.f};

    // A source: x[m_base + ms*16 + l15][i0 + quad]
    const float* xp = x + (size_t)(m_base + l15) * NIN + quad;
    // B source: coef[(i0+quad) * NOUT*8 + (n_base + ns*16 + l15) * 8]  (8 contiguous floats)
    const float* cp = coef + (size_t)quad * (NOUT * GS) + (size_t)(n_base + l15) * GS;

    for (int i0 = 0; i0 < NIN; i0 += 4) {
        // ---- issue B loads early (two dwordx4 per frag, 512B contiguous across lanes 0-15) ----
        f32x4 braw[4][2];
#pragma unroll
        for (int ns = 0; ns < 4; ++ns) {
            const float* p = cp + ns * (16 * GS);
            braw[ns][0] = *(const f32x4*)(p);
            braw[ns][1] = *(const f32x4*)(p + 4);
        }
        // ---- x scalars (one per lane per m-subtile) ----
        float xv[4];
#pragma unroll
        for (int ms = 0; ms < 4; ++ms)
            xv[ms] = xp[ms * 16 * NIN];

        // ---- A frags: 8 gaussian-bump basis values per lane, reference-exact semantics ----
        bf16x8 afrag[4];
#pragma unroll
        for (int ms = 0; ms < 4; ++ms) {
            float e[GS];
            float s = 0.f;
#pragma unroll
            for (int k = 0; k < GS; ++k) {
                float t = xv[ms] - g[k];
                e[k] = __builtin_amdgcn_exp2f(t * t * KE);   // underflows to 0 like np fp32
                s += e[k];
            }
            float rn = __builtin_amdgcn_rcpf(s + 1e-8f);
            bf16x8 fr;
#pragma unroll
            for (int k = 0; k < GS; ++k) fr[k] = f2bf(e[k] * rn);
            afrag[ms] = fr;
        }

        // ---- B frags: convert fp32 -> bf16 ----
        bf16x8 bfrag[4];
#pragma unroll
        for (int ns = 0; ns < 4; ++ns) {
            bf16x8 fr;
#pragma unroll
            for (int k = 0; k < 4; ++k) {
                fr[k]     = f2bf(braw[ns][0][k]);
                fr[k + 4] = f2bf(braw[ns][1][k]);
            }
            bfrag[ns] = fr;
        }

        // ---- 16 MFMAs: acc[ms][ns] += A(64x32 slice) * B(32x64 slice) ----
#pragma unroll
        for (int ms = 0; ms < 4; ++ms)
#pragma unroll
            for (int ns = 0; ns < 4; ++ns)
                acc[ms][ns] = __builtin_amdgcn_mfma_f32_16x16x32_bf16(
                    afrag[ms], bfrag[ns], acc[ms][ns], 0, 0, 0);

        xp += 4;
        cp += 4 * (NOUT * GS);
    }

    // ---- epilogue: C/D layout col = lane&15, row = quad*4 + reg ----
#pragma unroll
    for (int ms = 0; ms < 4; ++ms) {
#pragma unroll
        for (int ns = 0; ns < 4; ++ns) {
            const int col = n_base + ns * 16 + l15;
#pragma unroll
            for (int r = 0; r < 4; ++r) {
                const int row = m_base + ms * 16 + quad * 4 + r;
                out[(size_t)row * NOUT + col] = acc[ms][ns][r];
            }
        }
    }
}

extern "C" void kernel_launch(void* const* d_in, const int* in_sizes, int n_in,
                              void* d_out, int out_size, void* d_ws, size_t ws_size,
                              hipStream_t stream) {
    const float* x    = (const float*)d_in[0];
    const float* coef = (const float*)d_in[1];
    const float* grid = (const float*)d_in[2];
    float* out        = (float*)d_out;
    dim3 grd(BATCH / 128, NOUT / 128);   // 32 x 16 = 512 blocks = 2 blocks/CU
    kan_kernel<<<grd, 256, 0, stream>>>(x, coef, grid, out);
}

// Round 2
// 703.773 us; speedup vs baseline: 2.3899x; 2.3899x over previous
//
#include <hip/hip_runtime.h>
#include <hip/hip_bf16.h>

#define BATCH   4096
#define NIN     2048
#define NOUT    2048
#define GS      8

typedef __attribute__((ext_vector_type(8))) short  bf16x8;   // 8 bf16 = 4 VGPR (MFMA frag)
typedef __attribute__((ext_vector_type(4))) float  f32x4;

// round-to-nearest-even f32 -> bf16
__device__ __forceinline__ short f2bf(float f) {
    unsigned u = __builtin_bit_cast(unsigned, f);
    u += 0x7fffu + ((u >> 16) & 1u);
    return (short)(u >> 16);
}

__device__ __forceinline__ bf16x8 basis_bf16(float xv, const float* g) {
    const float KE = -7.2134752044448170f;   // -5 * log2(e)
    float e[GS], s = 0.f;
#pragma unroll
    for (int k = 0; k < GS; ++k) {
        float t = xv - g[k];
        e[k] = __builtin_amdgcn_exp2f(t * t * KE);
        s += e[k];
    }
    float rn = __builtin_amdgcn_rcpf(s + 1e-8f);
    bf16x8 fr;
#pragma unroll
    for (int k = 0; k < GS; ++k) fr[k] = f2bf(e[k] * rn);
    return fr;
}

// ============================ PASS 1: basis ============================
// A_ws[i][b*8+k] bf16 (i-major so pass-2 A-frag loads coalesce 256B).
// 64b x 32i tile, LDS transpose: x-read coalesced over i, A-write coalesced over b.
#define TB 64
#define TI 32
__global__ __launch_bounds__(256, 4)
void kan_basis_kernel(const float* __restrict__ x, const float* __restrict__ grid,
                      short* __restrict__ A_ws)
{
    __shared__ float tile[TB][TI + 1];
    const int b0 = blockIdx.y * TB;
    const int i0 = blockIdx.x * TI;
    const int t  = threadIdx.x;

    float g[GS];
#pragma unroll
    for (int k = 0; k < GS; ++k) g[k] = grid[k];

#pragma unroll
    for (int p = 0; p < (TB * TI) / 256; ++p) {          // 8 iters
        int idx = t + p * 256;
        int b_l = idx >> 5, i_l = idx & 31;
        tile[b_l][i_l] = x[(size_t)(b0 + b_l) * NIN + i0 + i_l];
    }
    __syncthreads();

#pragma unroll
    for (int it = 0; it < 8; ++it) {                     // 32b x 8i per iter
        int b_l = (t & 31) + 32 * (it & 1);
        int i_l = (t >> 5) + 8 * (it >> 1);
        bf16x8 fr = basis_bf16(tile[b_l][i_l], g);
        *(bf16x8*)(A_ws + (size_t)(i0 + i_l) * (BATCH * GS)
                        + (size_t)(b0 + b_l) * GS) = fr;
    }
}

// ========================= PASS 1b: coef -> bf16 =========================
__global__ __launch_bounds__(256, 8)
void kan_cvt_coef_kernel(const float* __restrict__ coef, short* __restrict__ B_ws)
{
    size_t idx = ((size_t)blockIdx.x * 256 + threadIdx.x) * 8;
    f32x4 a = *(const f32x4*)(coef + idx);
    f32x4 b = *(const f32x4*)(coef + idx + 4);
    bf16x8 fr;
#pragma unroll
    for (int k = 0; k < 4; ++k) { fr[k] = f2bf(a[k]); fr[k + 4] = f2bf(b[k]); }
    *(bf16x8*)(B_ws + idx) = fr;
}

// ============================ PASS 2: GEMM ============================
// C[b,j] = sum over K=NIN*8 of A[b,K] * B[K,j].  128x128 block tile, 4 waves
// of 64x64. LDS-free: A and B MFMA frags are direct dwordx4 loads,
// register ping-pong double buffer.
__global__ __launch_bounds__(256, 2)
void kan_gemm_kernel(const short* __restrict__ A_ws, const short* __restrict__ B_ws,
                     float* __restrict__ out)
{
    const int tid  = threadIdx.x;
    const int wave = tid >> 6;
    const int lane = tid & 63;
    const int l15  = lane & 15;
    const int quad = lane >> 4;

    const int wm = wave & 1;
    const int wn = wave >> 1;
    const int m_base = blockIdx.x * 128 + wm * 64;
    const int n_base = blockIdx.y * 128 + wn * 64;

    f32x4 acc[4][4];
#pragma unroll
    for (int a = 0; a < 4; ++a)
#pragma unroll
        for (int b = 0; b < 4; ++b)
            acc[a][b] = (f32x4){0.f, 0.f, 0.f, 0.f};

    // lane base pointers (quad selects the i-row within the K=32 slice)
    const short* ap = A_ws + (size_t)quad * (BATCH * GS) + (size_t)(m_base + l15) * GS;
    const short* bp = B_ws + (size_t)quad * (NOUT  * GS) + (size_t)(n_base + l15) * GS;

    auto loadA = [&](int i0, bf16x8* af) {
        const short* p = ap + (size_t)i0 * (BATCH * GS);
#pragma unroll
        for (int ms = 0; ms < 4; ++ms) af[ms] = *(const bf16x8*)(p + ms * 16 * GS);
    };
    auto loadB = [&](int i0, bf16x8* bf) {
        const short* p = bp + (size_t)i0 * (NOUT * GS);
#pragma unroll
        for (int ns = 0; ns < 4; ++ns) bf[ns] = *(const bf16x8*)(p + ns * 16 * GS);
    };

    bf16x8 A0[4], B0[4], A1[4], B1[4];
    loadA(0, A0); loadB(0, B0);

    for (int i0 = 0; i0 < NIN; i0 += 8) {
        loadA(i0 + 4, A1); loadB(i0 + 4, B1);
#pragma unroll
        for (int ms = 0; ms < 4; ++ms)
#pragma unroll
            for (int ns = 0; ns < 4; ++ns)
                acc[ms][ns] = __builtin_amdgcn_mfma_f32_16x16x32_bf16(
                    A0[ms], B0[ns], acc[ms][ns], 0, 0, 0);

        int nx = (i0 + 8 < NIN) ? i0 + 8 : 0;   // last iter: harmless dummy reload
        loadA(nx, A0); loadB(nx, B0);
#pragma unroll
        for (int ms = 0; ms < 4; ++ms)
#pragma unroll
            for (int ns = 0; ns < 4; ++ns)
                acc[ms][ns] = __builtin_amdgcn_mfma_f32_16x16x32_bf16(
                    A1[ms], B1[ns], acc[ms][ns], 0, 0, 0);
    }

    // C/D layout: col = lane&15, row = quad*4 + reg
#pragma unroll
    for (int ms = 0; ms < 4; ++ms)
#pragma unroll
        for (int ns = 0; ns < 4; ++ns) {
            const int col = n_base + ns * 16 + l15;
#pragma unroll
            for (int r = 0; r < 4; ++r) {
                const int row = m_base + ms * 16 + quad * 4 + r;
                out[(size_t)row * NOUT + col] = acc[ms][ns][r];
            }
        }
}

// ===================== fallback (round-1 fused kernel) =====================
__global__ __launch_bounds__(256, 2)
void kan_fused_kernel(const float* __restrict__ x, const float* __restrict__ coef,
                      const float* __restrict__ grid, float* __restrict__ out)
{
    const int tid  = threadIdx.x;
    const int wave = tid >> 6;
    const int lane = tid & 63;
    const int l15  = lane & 15;
    const int quad = lane >> 4;
    const int wm = wave & 1, wn = wave >> 1;
    const int m_base = blockIdx.x * 128 + wm * 64;
    const int n_base = blockIdx.y * 128 + wn * 64;

    float g[GS];
#pragma unroll
    for (int k = 0; k < GS; ++k) g[k] = grid[k];

    f32x4 acc[4][4];
#pragma unroll
    for (int a = 0; a < 4; ++a)
#pragma unroll
        for (int b = 0; b < 4; ++b) acc[a][b] = (f32x4){0.f, 0.f, 0.f, 0.f};

    const float* xp = x + (size_t)(m_base + l15) * NIN + quad;
    const float* cp = coef + (size_t)quad * (NOUT * GS) + (size_t)(n_base + l15) * GS;

    for (int i0 = 0; i0 < NIN; i0 += 4) {
        f32x4 braw[4][2];
#pragma unroll
        for (int ns = 0; ns < 4; ++ns) {
            const float* p = cp + ns * (16 * GS);
            braw[ns][0] = *(const f32x4*)(p);
            braw[ns][1] = *(const f32x4*)(p + 4);
        }
        bf16x8 afrag[4];
#pragma unroll
        for (int ms = 0; ms < 4; ++ms)
            afrag[ms] = basis_bf16(xp[ms * 16 * NIN], g);
        bf16x8 bfrag[4];
#pragma unroll
        for (int ns = 0; ns < 4; ++ns) {
            bf16x8 fr;
#pragma unroll
            for (int k = 0; k < 4; ++k) { fr[k] = f2bf(braw[ns][0][k]); fr[k+4] = f2bf(braw[ns][1][k]); }
            bfrag[ns] = fr;
        }
#pragma unroll
        for (int ms = 0; ms < 4; ++ms)
#pragma unroll
            for (int ns = 0; ns < 4; ++ns)
                acc[ms][ns] = __builtin_amdgcn_mfma_f32_16x16x32_bf16(
                    afrag[ms], bfrag[ns], acc[ms][ns], 0, 0, 0);
        xp += 4;
        cp += 4 * (NOUT * GS);
    }
#pragma unroll
    for (int ms = 0; ms < 4; ++ms)
#pragma unroll
        for (int ns = 0; ns < 4; ++ns) {
            const int col = n_base + ns * 16 + l15;
#pragma unroll
            for (int r = 0; r < 4; ++r)
                out[(size_t)(m_base + ms * 16 + quad * 4 + r) * NOUT + col] = acc[ms][ns][r];
        }
}

extern "C" void kernel_launch(void* const* d_in, const int* in_sizes, int n_in,
                              void* d_out, int out_size, void* d_ws, size_t ws_size,
                              hipStream_t stream) {
    const float* x    = (const float*)d_in[0];
    const float* coef = (const float*)d_in[1];
    const float* grid = (const float*)d_in[2];
    float* out        = (float*)d_out;

    const size_t a_elems = (size_t)NIN * BATCH * GS;   // 67.1M bf16 = 134 MB
    const size_t b_elems = (size_t)NIN * NOUT * GS;    // 33.6M bf16 =  67 MB
    const size_t need    = (a_elems + b_elems) * sizeof(short);

    if (ws_size >= need) {
        short* A_ws = (short*)d_ws;
        short* B_ws = A_ws + a_elems;

        dim3 g1(NIN / TI, BATCH / TB);                 // 64 x 64 blocks
        kan_basis_kernel<<<g1, 256, 0, stream>>>(x, grid, A_ws);

        int g1b = (int)(b_elems / 8 / 256);            // 16384 blocks
        kan_cvt_coef_kernel<<<g1b, 256, 0, stream>>>(coef, B_ws);

        dim3 g2(BATCH / 128, NOUT / 128);              // 32 x 16 = 512 blocks
        kan_gemm_kernel<<<g2, 256, 0, stream>>>(A_ws, B_ws, out);
    } else {
        dim3 grd(BATCH / 128, NOUT / 128);
        kan_fused_kernel<<<grd, 256, 0, stream>>>(x, coef, grid, out);
    }
}

// Round 3
// 615.709 us; speedup vs baseline: 2.7317x; 1.1430x over previous
//
#include <hip/hip_runtime.h>
#include <hip/hip_bf16.h>

#define BATCH   4096
#define NIN     2048
#define NOUT    2048
#define GS      8

typedef __attribute__((ext_vector_type(8))) short  bf16x8;   // 8 bf16 = 4 VGPR (MFMA frag)
typedef __attribute__((ext_vector_type(4))) float  f32x4;

// round-to-nearest-even f32 -> bf16
__device__ __forceinline__ short f2bf(float f) {
    unsigned u = __builtin_bit_cast(unsigned, f);
    u += 0x7fffu + ((u >> 16) & 1u);
    return (short)(u >> 16);
}

__device__ __forceinline__ bf16x8 basis_bf16(float xv, const float* g) {
    const float KE = -7.2134752044448170f;   // -5 * log2(e)
    float e[GS], s = 0.f;
#pragma unroll
    for (int k = 0; k < GS; ++k) {
        float t = xv - g[k];
        e[k] = __builtin_amdgcn_exp2f(t * t * KE);
        s += e[k];
    }
    float rn = __builtin_amdgcn_rcpf(s + 1e-8f);
    bf16x8 fr;
#pragma unroll
    for (int k = 0; k < GS; ++k) fr[k] = f2bf(e[k] * rn);
    return fr;
}

// ======================= PASS 1 (fused): basis + coef cvt =======================
// blocks [0, NCVT)            : coef fp32 -> bf16 (layout preserved)
// blocks [NCVT, NCVT+NBASIS)  : basis -> A_ws[i][b*8+k] bf16 (i-major)
#define TB 64
#define TI 32
#define NCVT   ((NIN * NOUT * GS) / 8 / 256)          // 16384
#define NBASIS ((NIN / TI) * (BATCH / TB))            // 64*64 = 4096

__global__ __launch_bounds__(256, 4)
void kan_prep_kernel(const float* __restrict__ x, const float* __restrict__ coef,
                     const float* __restrict__ grid,
                     short* __restrict__ A_ws, short* __restrict__ B_ws)
{
    __shared__ float tile[TB][TI + 1];
    const int t = threadIdx.x;

    if (blockIdx.x < NCVT) {
        // ---- coef conversion: 8 elems/thread, fully coalesced ----
        size_t idx = ((size_t)blockIdx.x * 256 + t) * 8;
        f32x4 a = *(const f32x4*)(coef + idx);
        f32x4 b = *(const f32x4*)(coef + idx + 4);
        bf16x8 fr;
#pragma unroll
        for (int k = 0; k < 4; ++k) { fr[k] = f2bf(a[k]); fr[k + 4] = f2bf(b[k]); }
        *(bf16x8*)(B_ws + idx) = fr;
        return;
    }

    // ---- basis: 64b x 32i tile with LDS transpose ----
    const int bid = blockIdx.x - NCVT;
    const int i0 = (bid & (NIN / TI - 1)) * TI;
    const int b0 = (bid / (NIN / TI)) * TB;

    float g[GS];
#pragma unroll
    for (int k = 0; k < GS; ++k) g[k] = grid[k];

#pragma unroll
    for (int p = 0; p < (TB * TI) / 256; ++p) {          // 8 iters, coalesced over i
        int idx = t + p * 256;
        int b_l = idx >> 5, i_l = idx & 31;
        tile[b_l][i_l] = x[(size_t)(b0 + b_l) * NIN + i0 + i_l];
    }
    __syncthreads();

#pragma unroll
    for (int it = 0; it < 8; ++it) {                     // writes coalesced over b
        int b_l = (t & 31) + 32 * (it & 1);
        int i_l = (t >> 5) + 8 * (it >> 1);
        bf16x8 fr = basis_bf16(tile[b_l][i_l], g);
        *(bf16x8*)(A_ws + (size_t)(i0 + i_l) * (BATCH * GS)
                        + (size_t)(b0 + b_l) * GS) = fr;
    }
}

// ============================ PASS 2: GEMM ============================
// C[b,j] over K = NIN*8.  128x128 block tile, 4 waves of 64x64.
// LDS-free, frag-direct dwordx4 loads, 4-deep register software pipeline.
__global__ __launch_bounds__(256, 2)
void kan_gemm_kernel(const short* __restrict__ A_ws, const short* __restrict__ B_ws,
                     float* __restrict__ out)
{
    const int tid  = threadIdx.x;
    const int wave = tid >> 6;
    const int lane = tid & 63;
    const int l15  = lane & 15;
    const int quad = lane >> 4;

    const int m_base = blockIdx.x * 128 + (wave & 1) * 64;
    const int n_base = blockIdx.y * 128 + (wave >> 1) * 64;

    f32x4 acc[4][4];
#pragma unroll
    for (int a = 0; a < 4; ++a)
#pragma unroll
        for (int b = 0; b < 4; ++b)
            acc[a][b] = (f32x4){0.f, 0.f, 0.f, 0.f};

    const short* ap = A_ws + (size_t)quad * (BATCH * GS) + (size_t)(m_base + l15) * GS;
    const short* bp = B_ws + (size_t)quad * (NOUT  * GS) + (size_t)(n_base + l15) * GS;

    auto loadA = [&](int i0, bf16x8* af) {
        const short* p = ap + (size_t)i0 * (BATCH * GS);
#pragma unroll
        for (int ms = 0; ms < 4; ++ms) af[ms] = *(const bf16x8*)(p + ms * 16 * GS);
    };
    auto loadB = [&](int i0, bf16x8* bf) {
        const short* p = bp + (size_t)i0 * (NOUT * GS);
#pragma unroll
        for (int ns = 0; ns < 4; ++ns) bf[ns] = *(const bf16x8*)(p + ns * 16 * GS);
    };

    // 4-deep pipeline: buffer s holds K-step (i0 + 4*s)
    bf16x8 Ab[4][4], Bb[4][4];
#pragma unroll
    for (int s = 0; s < 4; ++s) { loadA(s * 4, Ab[s]); loadB(s * 4, Bb[s]); }

    for (int i0 = 0; i0 < NIN; i0 += 16) {
#pragma unroll
        for (int s = 0; s < 4; ++s) {
            // consume buffer s (loads issued 4 sub-steps ago)
#pragma unroll
            for (int ms = 0; ms < 4; ++ms)
#pragma unroll
                for (int ns = 0; ns < 4; ++ns)
                    acc[ms][ns] = __builtin_amdgcn_mfma_f32_16x16x32_bf16(
                        Ab[s][ms], Bb[s][ns], acc[ms][ns], 0, 0, 0);
            // refill buffer s for step i0+16+4s (wraps harmlessly on last iter)
            int nxt = (i0 + 16 + s * 4) & (NIN - 1);
            loadA(nxt, Ab[s]); loadB(nxt, Bb[s]);
        }
    }

    // C/D layout: col = lane&15, row = quad*4 + reg
#pragma unroll
    for (int ms = 0; ms < 4; ++ms)
#pragma unroll
        for (int ns = 0; ns < 4; ++ns) {
            const int col = n_base + ns * 16 + l15;
#pragma unroll
            for (int r = 0; r < 4; ++r) {
                const int row = m_base + ms * 16 + quad * 4 + r;
                out[(size_t)row * NOUT + col] = acc[ms][ns][r];
            }
        }
}

// ===================== fallback (round-1 fused kernel) =====================
__global__ __launch_bounds__(256, 2)
void kan_fused_kernel(const float* __restrict__ x, const float* __restrict__ coef,
                      const float* __restrict__ grid, float* __restrict__ out)
{
    const int tid  = threadIdx.x;
    const int wave = tid >> 6;
    const int lane = tid & 63;
    const int l15  = lane & 15;
    const int quad = lane >> 4;
    const int m_base = blockIdx.x * 128 + (wave & 1) * 64;
    const int n_base = blockIdx.y * 128 + (wave >> 1) * 64;

    float g[GS];
#pragma unroll
    for (int k = 0; k < GS; ++k) g[k] = grid[k];

    f32x4 acc[4][4];
#pragma unroll
    for (int a = 0; a < 4; ++a)
#pragma unroll
        for (int b = 0; b < 4; ++b) acc[a][b] = (f32x4){0.f, 0.f, 0.f, 0.f};

    const float* xp = x + (size_t)(m_base + l15) * NIN + quad;
    const float* cp = coef + (size_t)quad * (NOUT * GS) + (size_t)(n_base + l15) * GS;

    for (int i0 = 0; i0 < NIN; i0 += 4) {
        f32x4 braw[4][2];
#pragma unroll
        for (int ns = 0; ns < 4; ++ns) {
            const float* p = cp + ns * (16 * GS);
            braw[ns][0] = *(const f32x4*)(p);
            braw[ns][1] = *(const f32x4*)(p + 4);
        }
        bf16x8 afrag[4];
#pragma unroll
        for (int ms = 0; ms < 4; ++ms)
            afrag[ms] = basis_bf16(xp[ms * 16 * NIN], g);
        bf16x8 bfrag[4];
#pragma unroll
        for (int ns = 0; ns < 4; ++ns) {
            bf16x8 fr;
#pragma unroll
            for (int k = 0; k < 4; ++k) { fr[k] = f2bf(braw[ns][0][k]); fr[k+4] = f2bf(braw[ns][1][k]); }
            bfrag[ns] = fr;
        }
#pragma unroll
        for (int ms = 0; ms < 4; ++ms)
#pragma unroll
            for (int ns = 0; ns < 4; ++ns)
                acc[ms][ns] = __builtin_amdgcn_mfma_f32_16x16x32_bf16(
                    afrag[ms], bfrag[ns], acc[ms][ns], 0, 0, 0);
        xp += 4;
        cp += 4 * (NOUT * GS);
    }
#pragma unroll
    for (int ms = 0; ms < 4; ++ms)
#pragma unroll
        for (int ns = 0; ns < 4; ++ns) {
            const int col = n_base + ns * 16 + l15;
#pragma unroll
            for (int r = 0; r < 4; ++r)
                out[(size_t)(m_base + ms * 16 + quad * 4 + r) * NOUT + col] = acc[ms][ns][r];
        }
}

extern "C" void kernel_launch(void* const* d_in, const int* in_sizes, int n_in,
                              void* d_out, int out_size, void* d_ws, size_t ws_size,
                              hipStream_t stream) {
    const float* x    = (const float*)d_in[0];
    const float* coef = (const float*)d_in[1];
    const float* grid = (const float*)d_in[2];
    float* out        = (float*)d_out;

    const size_t a_elems = (size_t)NIN * BATCH * GS;   // 134 MB bf16
    const size_t b_elems = (size_t)NIN * NOUT * GS;    //  67 MB bf16
    const size_t need    = (a_elems + b_elems) * sizeof(short);

    if (ws_size >= need) {
        short* A_ws = (short*)d_ws;
        short* B_ws = A_ws + a_elems;

        kan_prep_kernel<<<NCVT + NBASIS, 256, 0, stream>>>(x, coef, grid, A_ws, B_ws);

        dim3 g2(BATCH / 128, NOUT / 128);              // 32 x 16 = 512 blocks
        kan_gemm_kernel<<<g2, 256, 0, stream>>>(A_ws, B_ws, out);
    } else {
        dim3 grd(BATCH / 128, NOUT / 128);
        kan_fused_kernel<<<grd, 256, 0, stream>>>(x, coef, grid, out);
    }
}

// Round 4
// 541.629 us; speedup vs baseline: 3.1054x; 1.1368x over previous
//
#include <hip/hip_runtime.h>
#include <hip/hip_bf16.h>

#define BATCH   4096
#define NIN     2048
#define NOUT    2048
#define GS      8

typedef __attribute__((ext_vector_type(8))) short  bf16x8;   // 8 bf16 = 4 VGPR (MFMA frag)
typedef __attribute__((ext_vector_type(4))) short  bf16x4;   // 8B
typedef __attribute__((ext_vector_type(4))) float  f32x4;

// round-to-nearest-even f32 -> bf16
__device__ __forceinline__ short f2bf(float f) {
    unsigned u = __builtin_bit_cast(unsigned, f);
    u += 0x7fffu + ((u >> 16) & 1u);
    return (short)(u >> 16);
}

__device__ __forceinline__ bf16x8 basis_bf16(float xv, const float* g) {
    const float KE = -7.2134752044448170f;   // -5 * log2(e)
    float e[GS], s = 0.f;
#pragma unroll
    for (int k = 0; k < GS; ++k) {
        float t = xv - g[k];
        e[k] = __builtin_amdgcn_exp2f(t * t * KE);
        s += e[k];
    }
    float rn = __builtin_amdgcn_rcpf(s + 1e-8f);
    bf16x8 fr;
#pragma unroll
    for (int k = 0; k < GS; ++k) fr[k] = f2bf(e[k] * rn);
    return fr;
}

// async 16B global -> LDS DMA (no VGPR round trip; LDS dest = wave base + lane*16)
__device__ __forceinline__ void async16(const void* g, void* l) {
    __builtin_amdgcn_global_load_lds(
        (const __attribute__((address_space(1))) unsigned*)g,
        (__attribute__((address_space(3))) unsigned*)l, 16, 0, 0);
}

// ======================= PASS 1: prep (cvt + basis), grid-stride =======================
// A_ws[i][b*8+k] bf16 (i-major), B_ws = bf16 coef (layout preserved)
#define PREP_BLOCKS 2048
#define TB 64
#define TI 32

__global__ __launch_bounds__(256, 4)
void kan_prep_kernel(const float* __restrict__ x, const float* __restrict__ coef,
                     const float* __restrict__ grid,
                     short* __restrict__ A_ws, short* __restrict__ B_ws)
{
    const int t = threadIdx.x;

    // ---- coef fp32 -> bf16: 8192 chunks of 4096 floats, fully coalesced ----
    for (int c = blockIdx.x; c < (NIN * NOUT * GS) / 4096; c += PREP_BLOCKS) {
        const float* src = coef + (size_t)c * 4096;
        short*       dst = B_ws + (size_t)c * 4096;
        f32x4 v[4];
#pragma unroll
        for (int j = 0; j < 4; ++j)                  // 4 KB per load instr / wave-contig
            v[j] = *(const f32x4*)(src + j * 1024 + t * 4);
#pragma unroll
        for (int j = 0; j < 4; ++j) {
            bf16x4 o;
#pragma unroll
            for (int k = 0; k < 4; ++k) o[k] = f2bf(v[j][k]);
            *(bf16x4*)(dst + j * 1024 + t * 4) = o;  // 8B contiguous stores
        }
    }

    // ---- basis: 64b x 32i tiles with LDS transpose ----
    __shared__ float tile[TB][TI + 1];
    float g[GS];
#pragma unroll
    for (int k = 0; k < GS; ++k) g[k] = grid[k];

    for (int job = blockIdx.x; job < (NIN / TI) * (BATCH / TB); job += PREP_BLOCKS) {
        const int i0 = (job & (NIN / TI - 1)) * TI;
        const int b0 = (job / (NIN / TI)) * TB;
        __syncthreads();                             // protect tile from previous job
#pragma unroll
        for (int p = 0; p < (TB * TI) / 256; ++p) {  // reads coalesced over i
            int idx = t + p * 256;
            int b_l = idx >> 5, i_l = idx & 31;
            tile[b_l][i_l] = x[(size_t)(b0 + b_l) * NIN + i0 + i_l];
        }
        __syncthreads();
#pragma unroll
        for (int it = 0; it < 8; ++it) {             // writes coalesced over b
            int b_l = (t & 31) + 32 * (it & 1);
            int i_l = (t >> 5) + 8 * (it >> 1);
            bf16x8 fr = basis_bf16(tile[b_l][i_l], g);
            *(bf16x8*)(A_ws + (size_t)(i0 + i_l) * (BATCH * GS)
                            + (size_t)(b0 + b_l) * GS) = fr;
        }
    }
}

// ============================ PASS 2: GEMM ============================
// 128x128 tile, 4 waves (2x2 of 64x64). K-step = 8 i's (K=64).
// A/B K-slices DMA'd to LDS via global_load_lds x16 (m97 structure),
// 32 MFMAs per barrier pair.
__global__ __launch_bounds__(256, 2)
void kan_gemm_kernel(const short* __restrict__ A_ws, const short* __restrict__ B_ws,
                     float* __restrict__ out)
{
    __shared__ __align__(16) char As[16384];   // 8 i-slices x 128 rows x 16B
    __shared__ __align__(16) char Bs[16384];

    const int t    = threadIdx.x;
    const int wave = t >> 6;
    const int lane = t & 63;
    const int l15  = lane & 15;
    const int quad = lane >> 4;
    const int wm = wave & 1, wn = wave >> 1;
    const int m_blk = blockIdx.x * 128, n_blk = blockIdx.y * 128;

    f32x4 acc[4][4];
#pragma unroll
    for (int a = 0; a < 4; ++a)
#pragma unroll
        for (int b = 0; b < 4; ++b)
            acc[a][b] = (f32x4){0.f, 0.f, 0.f, 0.f};

    // per-i-slice sources: 2 KB contiguous (128 rows/cols x 16B)
    const char* Abase = (const char*)A_ws + (size_t)m_blk * (GS * 2);
    const char* Bbase = (const char*)B_ws + (size_t)n_blk * (GS * 2);
    const size_t strideA = (size_t)BATCH * GS * 2;   // 64 KB per i
    const size_t strideB = (size_t)NOUT  * GS * 2;   // 32 KB per i

    // DMA plan: 4 instr x 256 thr x 16B = 16 KB per tile.
    // off = j*4096 + t*16 ; i_loc = off>>11 (wave-uniform), rem = off & 2047.
    int dma_off[4], dma_iloc[4], dma_rem[4];
#pragma unroll
    for (int j = 0; j < 4; ++j) {
        dma_off[j]  = j * 4096 + t * 16;
        dma_iloc[j] = dma_off[j] >> 11;
        dma_rem[j]  = dma_off[j] & 2047;
    }

    for (int i0 = 0; i0 < NIN; i0 += 8) {
#pragma unroll
        for (int j = 0; j < 4; ++j) {
            const size_t i = (size_t)(i0 + dma_iloc[j]);
            async16(Abase + i * strideA + dma_rem[j], As + dma_off[j]);
            async16(Bbase + i * strideB + dma_rem[j], Bs + dma_off[j]);
        }
        __syncthreads();   // compiler drains vmcnt before barrier -> LDS valid

#pragma unroll
        for (int s = 0; s < 2; ++s) {
            const int iloc = s * 4 + quad;
            bf16x8 af[4], bf[4];
#pragma unroll
            for (int ms = 0; ms < 4; ++ms)
                af[ms] = *(const bf16x8*)(As + (size_t)(iloc * 128 + wm * 64 + ms * 16 + l15) * 16);
#pragma unroll
            for (int ns = 0; ns < 4; ++ns)
                bf[ns] = *(const bf16x8*)(Bs + (size_t)(iloc * 128 + wn * 64 + ns * 16 + l15) * 16);
#pragma unroll
            for (int ms = 0; ms < 4; ++ms)
#pragma unroll
                for (int ns = 0; ns < 4; ++ns)
                    acc[ms][ns] = __builtin_amdgcn_mfma_f32_16x16x32_bf16(
                        af[ms], bf[ns], acc[ms][ns], 0, 0, 0);
        }
        __syncthreads();   // before next iteration overwrites LDS
    }

    // C/D layout: col = lane&15, row = quad*4 + reg
    const int m_base = m_blk + wm * 64;
    const int n_base = n_blk + wn * 64;
#pragma unroll
    for (int ms = 0; ms < 4; ++ms)
#pragma unroll
        for (int ns = 0; ns < 4; ++ns) {
            const int col = n_base + ns * 16 + l15;
#pragma unroll
            for (int r = 0; r < 4; ++r) {
                const int row = m_base + ms * 16 + quad * 4 + r;
                out[(size_t)row * NOUT + col] = acc[ms][ns][r];
            }
        }
}

// ===================== fallback (round-1 fused kernel) =====================
__global__ __launch_bounds__(256, 2)
void kan_fused_kernel(const float* __restrict__ x, const float* __restrict__ coef,
                      const float* __restrict__ grid, float* __restrict__ out)
{
    const int tid  = threadIdx.x;
    const int wave = tid >> 6;
    const int lane = tid & 63;
    const int l15  = lane & 15;
    const int quad = lane >> 4;
    const int m_base = blockIdx.x * 128 + (wave & 1) * 64;
    const int n_base = blockIdx.y * 128 + (wave >> 1) * 64;

    float g[GS];
#pragma unroll
    for (int k = 0; k < GS; ++k) g[k] = grid[k];

    f32x4 acc[4][4];
#pragma unroll
    for (int a = 0; a < 4; ++a)
#pragma unroll
        for (int b = 0; b < 4; ++b) acc[a][b] = (f32x4){0.f, 0.f, 0.f, 0.f};

    const float* xp = x + (size_t)(m_base + l15) * NIN + quad;
    const float* cp = coef + (size_t)quad * (NOUT * GS) + (size_t)(n_base + l15) * GS;

    for (int i0 = 0; i0 < NIN; i0 += 4) {
        f32x4 braw[4][2];
#pragma unroll
        for (int ns = 0; ns < 4; ++ns) {
            const float* p = cp + ns * (16 * GS);
            braw[ns][0] = *(const f32x4*)(p);
            braw[ns][1] = *(const f32x4*)(p + 4);
        }
        bf16x8 afrag[4];
#pragma unroll
        for (int ms = 0; ms < 4; ++ms)
            afrag[ms] = basis_bf16(xp[ms * 16 * NIN], g);
        bf16x8 bfrag[4];
#pragma unroll
        for (int ns = 0; ns < 4; ++ns) {
            bf16x8 fr;
#pragma unroll
            for (int k = 0; k < 4; ++k) { fr[k] = f2bf(braw[ns][0][k]); fr[k+4] = f2bf(braw[ns][1][k]); }
            bfrag[ns] = fr;
        }
#pragma unroll
        for (int ms = 0; ms < 4; ++ms)
#pragma unroll
            for (int ns = 0; ns < 4; ++ns)
                acc[ms][ns] = __builtin_amdgcn_mfma_f32_16x16x32_bf16(
                    afrag[ms], bfrag[ns], acc[ms][ns], 0, 0, 0);
        xp += 4;
        cp += 4 * (NOUT * GS);
    }
#pragma unroll
    for (int ms = 0; ms < 4; ++ms)
#pragma unroll
        for (int ns = 0; ns < 4; ++ns) {
            const int col = n_base + ns * 16 + l15;
#pragma unroll
            for (int r = 0; r < 4; ++r)
                out[(size_t)(m_base + ms * 16 + quad * 4 + r) * NOUT + col] = acc[ms][ns][r];
        }
}

extern "C" void kernel_launch(void* const* d_in, const int* in_sizes, int n_in,
                              void* d_out, int out_size, void* d_ws, size_t ws_size,
                              hipStream_t stream) {
    const float* x    = (const float*)d_in[0];
    const float* coef = (const float*)d_in[1];
    const float* grid = (const float*)d_in[2];
    float* out        = (float*)d_out;

    const size_t a_elems = (size_t)NIN * BATCH * GS;   // 134 MB bf16
    const size_t b_elems = (size_t)NIN * NOUT * GS;    //  67 MB bf16
    const size_t need    = (a_elems + b_elems) * sizeof(short);

    if (ws_size >= need) {
        short* A_ws = (short*)d_ws;
        short* B_ws = A_ws + a_elems;

        kan_prep_kernel<<<PREP_BLOCKS, 256, 0, stream>>>(x, coef, grid, A_ws, B_ws);

        dim3 g2(BATCH / 128, NOUT / 128);              // 32 x 16 = 512 blocks
        kan_gemm_kernel<<<g2, 256, 0, stream>>>(A_ws, B_ws, out);
    } else {
        dim3 grd(BATCH / 128, NOUT / 128);
        kan_fused_kernel<<<grd, 256, 0, stream>>>(x, coef, grid, out);
    }
}

// Round 5
// 498.829 us; speedup vs baseline: 3.3718x; 1.0858x over previous
//
#include <hip/hip_runtime.h>
#include <hip/hip_bf16.h>

#define BATCH   4096
#define NIN     2048
#define NOUT    2048
#define GS      8

typedef __attribute__((ext_vector_type(8))) short  bf16x8;   // 8 bf16 = 4 VGPR (MFMA frag)
typedef __attribute__((ext_vector_type(4))) short  bf16x4;   // 8B
typedef __attribute__((ext_vector_type(4))) float  f32x4;

// round-to-nearest-even f32 -> bf16
__device__ __forceinline__ short f2bf(float f) {
    unsigned u = __builtin_bit_cast(unsigned, f);
    u += 0x7fffu + ((u >> 16) & 1u);
    return (short)(u >> 16);
}

__device__ __forceinline__ bf16x8 basis_bf16(float xv, const float* g) {
    const float KE = -7.2134752044448170f;   // -5 * log2(e)
    float e[GS], s = 0.f;
#pragma unroll
    for (int k = 0; k < GS; ++k) {
        float t = xv - g[k];
        e[k] = __builtin_amdgcn_exp2f(t * t * KE);
        s += e[k];
    }
    float rn = __builtin_amdgcn_rcpf(s + 1e-8f);
    bf16x8 fr;
#pragma unroll
    for (int k = 0; k < GS; ++k) fr[k] = f2bf(e[k] * rn);
    return fr;
}

// async 16B global -> LDS DMA (no VGPR round trip; LDS dest = wave base + lane*16)
__device__ __forceinline__ void async16(const void* g, void* l) {
    __builtin_amdgcn_global_load_lds(
        (const __attribute__((address_space(1))) unsigned*)g,
        (__attribute__((address_space(3))) unsigned*)l, 16, 0, 0);
}

// ======================= PASS 1: prep (cvt + basis), grid-stride =======================
// A_ws[i][b*8+k] bf16 (i-major), B_ws = bf16 coef (layout preserved)
#define PREP_BLOCKS 4096
#define TB 64
#define TI 32

__global__ __launch_bounds__(256, 4)
void kan_prep_kernel(const float* __restrict__ x, const float* __restrict__ coef,
                     const float* __restrict__ grid,
                     short* __restrict__ A_ws, short* __restrict__ B_ws)
{
    const int t = threadIdx.x;

    // ---- coef fp32 -> bf16: 8192 chunks of 4096 floats, fully coalesced.
    // NT loads: coef is read-once -> keep it out of L2/L3 so A_ws/B_ws stay resident for GEMM.
    for (int c = blockIdx.x; c < (NIN * NOUT * GS) / 4096; c += PREP_BLOCKS) {
        const float* src = coef + (size_t)c * 4096;
        short*       dst = B_ws + (size_t)c * 4096;
        f32x4 v[4];
#pragma unroll
        for (int j = 0; j < 4; ++j)
            v[j] = __builtin_nontemporal_load((const f32x4*)(src + j * 1024 + t * 4));
#pragma unroll
        for (int j = 0; j < 4; ++j) {
            bf16x4 o;
#pragma unroll
            for (int k = 0; k < 4; ++k) o[k] = f2bf(v[j][k]);
            *(bf16x4*)(dst + j * 1024 + t * 4) = o;
        }
    }

    // ---- basis: 64b x 32i tiles with LDS transpose ----
    __shared__ float tile[TB][TI + 1];
    float g[GS];
#pragma unroll
    for (int k = 0; k < GS; ++k) g[k] = grid[k];

    for (int job = blockIdx.x; job < (NIN / TI) * (BATCH / TB); job += PREP_BLOCKS) {
        const int i0 = (job & (NIN / TI - 1)) * TI;
        const int b0 = (job / (NIN / TI)) * TB;
        __syncthreads();                             // protect tile from previous job
#pragma unroll
        for (int p = 0; p < (TB * TI) / 256; ++p) {  // reads coalesced over i
            int idx = t + p * 256;
            int b_l = idx >> 5, i_l = idx & 31;
            tile[b_l][i_l] = x[(size_t)(b0 + b_l) * NIN + i0 + i_l];
        }
        __syncthreads();
#pragma unroll
        for (int it = 0; it < 8; ++it) {             // writes coalesced over b
            int b_l = (t & 31) + 32 * (it & 1);
            int i_l = (t >> 5) + 8 * (it >> 1);
            bf16x8 fr = basis_bf16(tile[b_l][i_l], g);
            *(bf16x8*)(A_ws + (size_t)(i0 + i_l) * (BATCH * GS)
                            + (size_t)(b0 + b_l) * GS) = fr;
        }
    }
}

// ============================ PASS 2: GEMM (split-K=2) ============================
// 128x128 tile, 4 waves (2x2 of 64x64). K-step = 8 i's (K=64), LDS DMA (m97 structure).
// blockIdx.z selects K-half; partials to P. 1024 blocks = 4 blocks/CU.
__global__ __launch_bounds__(256, 4)
void kan_gemm_splitk(const short* __restrict__ A_ws, const short* __restrict__ B_ws,
                     float* __restrict__ P)
{
    __shared__ __align__(16) char As[16384];   // 8 i-slices x 128 rows x 16B
    __shared__ __align__(16) char Bs[16384];

    const int t    = threadIdx.x;
    const int wave = t >> 6;
    const int lane = t & 63;
    const int l15  = lane & 15;
    const int quad = lane >> 4;
    const int wm = wave & 1, wn = wave >> 1;
    const int m_blk = blockIdx.x * 128, n_blk = blockIdx.y * 128;
    const int z = blockIdx.z;

    f32x4 acc[4][4];
#pragma unroll
    for (int a = 0; a < 4; ++a)
#pragma unroll
        for (int b = 0; b < 4; ++b)
            acc[a][b] = (f32x4){0.f, 0.f, 0.f, 0.f};

    const char* Abase = (const char*)A_ws + (size_t)m_blk * (GS * 2);
    const char* Bbase = (const char*)B_ws + (size_t)n_blk * (GS * 2);
    const size_t strideA = (size_t)BATCH * GS * 2;   // 64 KB per i
    const size_t strideB = (size_t)NOUT  * GS * 2;   // 32 KB per i

    int dma_off[4], dma_iloc[4], dma_rem[4];
#pragma unroll
    for (int j = 0; j < 4; ++j) {
        dma_off[j]  = j * 4096 + t * 16;
        dma_iloc[j] = dma_off[j] >> 11;
        dma_rem[j]  = dma_off[j] & 2047;
    }

    const int i_lo = z * (NIN / 2), i_hi = i_lo + (NIN / 2);
    for (int i0 = i_lo; i0 < i_hi; i0 += 8) {
#pragma unroll
        for (int j = 0; j < 4; ++j) {
            const size_t i = (size_t)(i0 + dma_iloc[j]);
            async16(Abase + i * strideA + dma_rem[j], As + dma_off[j]);
            async16(Bbase + i * strideB + dma_rem[j], Bs + dma_off[j]);
        }
        __syncthreads();

#pragma unroll
        for (int s = 0; s < 2; ++s) {
            const int iloc = s * 4 + quad;
            bf16x8 af[4], bf[4];
#pragma unroll
            for (int ms = 0; ms < 4; ++ms)
                af[ms] = *(const bf16x8*)(As + (size_t)(iloc * 128 + wm * 64 + ms * 16 + l15) * 16);
#pragma unroll
            for (int ns = 0; ns < 4; ++ns)
                bf[ns] = *(const bf16x8*)(Bs + (size_t)(iloc * 128 + wn * 64 + ns * 16 + l15) * 16);
#pragma unroll
            for (int ms = 0; ms < 4; ++ms)
#pragma unroll
                for (int ns = 0; ns < 4; ++ns)
                    acc[ms][ns] = __builtin_amdgcn_mfma_f32_16x16x32_bf16(
                        af[ms], bf[ns], acc[ms][ns], 0, 0, 0);
        }
        __syncthreads();
    }

    float* Pz = P + (size_t)z * ((size_t)BATCH * NOUT);
    const int m_base = m_blk + wm * 64;
    const int n_base = n_blk + wn * 64;
#pragma unroll
    for (int ms = 0; ms < 4; ++ms)
#pragma unroll
        for (int ns = 0; ns < 4; ++ns) {
            const int col = n_base + ns * 16 + l15;
#pragma unroll
            for (int r = 0; r < 4; ++r) {
                const int row = m_base + ms * 16 + quad * 4 + r;
                Pz[(size_t)row * NOUT + col] = acc[ms][ns][r];
            }
        }
}

// ============================ PASS 3: reduce ============================
__global__ __launch_bounds__(256, 4)
void kan_reduce_kernel(const float* __restrict__ P, float* __restrict__ out)
{
    const size_t n4 = (size_t)BATCH * NOUT / 4;     // 2,097,152 f32x4 groups
    for (size_t idx = (size_t)blockIdx.x * 256 + threadIdx.x; idx < n4;
         idx += (size_t)1024 * 256) {
        f32x4 a = ((const f32x4*)P)[idx];
        f32x4 b = ((const f32x4*)P)[idx + n4];
        ((f32x4*)out)[idx] = a + b;
    }
}

// ==================== fallback A: single-K GEMM (round-4 proven) ====================
__global__ __launch_bounds__(256, 2)
void kan_gemm_kernel(const short* __restrict__ A_ws, const short* __restrict__ B_ws,
                     float* __restrict__ out)
{
    __shared__ __align__(16) char As[16384];
    __shared__ __align__(16) char Bs[16384];

    const int t    = threadIdx.x;
    const int wave = t >> 6;
    const int lane = t & 63;
    const int l15  = lane & 15;
    const int quad = lane >> 4;
    const int wm = wave & 1, wn = wave >> 1;
    const int m_blk = blockIdx.x * 128, n_blk = blockIdx.y * 128;

    f32x4 acc[4][4];
#pragma unroll
    for (int a = 0; a < 4; ++a)
#pragma unroll
        for (int b = 0; b < 4; ++b)
            acc[a][b] = (f32x4){0.f, 0.f, 0.f, 0.f};

    const char* Abase = (const char*)A_ws + (size_t)m_blk * (GS * 2);
    const char* Bbase = (const char*)B_ws + (size_t)n_blk * (GS * 2);
    const size_t strideA = (size_t)BATCH * GS * 2;
    const size_t strideB = (size_t)NOUT  * GS * 2;

    int dma_off[4], dma_iloc[4], dma_rem[4];
#pragma unroll
    for (int j = 0; j < 4; ++j) {
        dma_off[j]  = j * 4096 + t * 16;
        dma_iloc[j] = dma_off[j] >> 11;
        dma_rem[j]  = dma_off[j] & 2047;
    }

    for (int i0 = 0; i0 < NIN; i0 += 8) {
#pragma unroll
        for (int j = 0; j < 4; ++j) {
            const size_t i = (size_t)(i0 + dma_iloc[j]);
            async16(Abase + i * strideA + dma_rem[j], As + dma_off[j]);
            async16(Bbase + i * strideB + dma_rem[j], Bs + dma_off[j]);
        }
        __syncthreads();
#pragma unroll
        for (int s = 0; s < 2; ++s) {
            const int iloc = s * 4 + quad;
            bf16x8 af[4], bf[4];
#pragma unroll
            for (int ms = 0; ms < 4; ++ms)
                af[ms] = *(const bf16x8*)(As + (size_t)(iloc * 128 + wm * 64 + ms * 16 + l15) * 16);
#pragma unroll
            for (int ns = 0; ns < 4; ++ns)
                bf[ns] = *(const bf16x8*)(Bs + (size_t)(iloc * 128 + wn * 64 + ns * 16 + l15) * 16);
#pragma unroll
            for (int ms = 0; ms < 4; ++ms)
#pragma unroll
                for (int ns = 0; ns < 4; ++ns)
                    acc[ms][ns] = __builtin_amdgcn_mfma_f32_16x16x32_bf16(
                        af[ms], bf[ns], acc[ms][ns], 0, 0, 0);
        }
        __syncthreads();
    }

    const int m_base = m_blk + wm * 64;
    const int n_base = n_blk + wn * 64;
#pragma unroll
    for (int ms = 0; ms < 4; ++ms)
#pragma unroll
        for (int ns = 0; ns < 4; ++ns) {
            const int col = n_base + ns * 16 + l15;
#pragma unroll
            for (int r = 0; r < 4; ++r) {
                const int row = m_base + ms * 16 + quad * 4 + r;
                out[(size_t)row * NOUT + col] = acc[ms][ns][r];
            }
        }
}

// ==================== fallback B: fused (no workspace) ====================
__global__ __launch_bounds__(256, 2)
void kan_fused_kernel(const float* __restrict__ x, const float* __restrict__ coef,
                      const float* __restrict__ grid, float* __restrict__ out)
{
    const int tid  = threadIdx.x;
    const int wave = tid >> 6;
    const int lane = tid & 63;
    const int l15  = lane & 15;
    const int quad = lane >> 4;
    const int m_base = blockIdx.x * 128 + (wave & 1) * 64;
    const int n_base = blockIdx.y * 128 + (wave >> 1) * 64;

    float g[GS];
#pragma unroll
    for (int k = 0; k < GS; ++k) g[k] = grid[k];

    f32x4 acc[4][4];
#pragma unroll
    for (int a = 0; a < 4; ++a)
#pragma unroll
        for (int b = 0; b < 4; ++b) acc[a][b] = (f32x4){0.f, 0.f, 0.f, 0.f};

    const float* xp = x + (size_t)(m_base + l15) * NIN + quad;
    const float* cp = coef + (size_t)quad * (NOUT * GS) + (size_t)(n_base + l15) * GS;

    for (int i0 = 0; i0 < NIN; i0 += 4) {
        f32x4 braw[4][2];
#pragma unroll
        for (int ns = 0; ns < 4; ++ns) {
            const float* p = cp + ns * (16 * GS);
            braw[ns][0] = *(const f32x4*)(p);
            braw[ns][1] = *(const f32x4*)(p + 4);
        }
        bf16x8 afrag[4];
#pragma unroll
        for (int ms = 0; ms < 4; ++ms)
            afrag[ms] = basis_bf16(xp[ms * 16 * NIN], g);
        bf16x8 bfrag[4];
#pragma unroll
        for (int ns = 0; ns < 4; ++ns) {
            bf16x8 fr;
#pragma unroll
            for (int k = 0; k < 4; ++k) { fr[k] = f2bf(braw[ns][0][k]); fr[k+4] = f2bf(braw[ns][1][k]); }
            bfrag[ns] = fr;
        }
#pragma unroll
        for (int ms = 0; ms < 4; ++ms)
#pragma unroll
            for (int ns = 0; ns < 4; ++ns)
                acc[ms][ns] = __builtin_amdgcn_mfma_f32_16x16x32_bf16(
                    afrag[ms], bfrag[ns], acc[ms][ns], 0, 0, 0);
        xp += 4;
        cp += 4 * (NOUT * GS);
    }
#pragma unroll
    for (int ms = 0; ms < 4; ++ms)
#pragma unroll
        for (int ns = 0; ns < 4; ++ns) {
            const int col = n_base + ns * 16 + l15;
#pragma unroll
            for (int r = 0; r < 4; ++r)
                out[(size_t)(m_base + ms * 16 + quad * 4 + r) * NOUT + col] = acc[ms][ns][r];
        }
}

extern "C" void kernel_launch(void* const* d_in, const int* in_sizes, int n_in,
                              void* d_out, int out_size, void* d_ws, size_t ws_size,
                              hipStream_t stream) {
    const float* x    = (const float*)d_in[0];
    const float* coef = (const float*)d_in[1];
    const float* grid = (const float*)d_in[2];
    float* out        = (float*)d_out;

    const size_t a_elems = (size_t)NIN * BATCH * GS;         // 67.1M shorts = 134 MB
    const size_t b_elems = (size_t)NIN * NOUT * GS;          // 33.5M shorts =  67 MB
    const size_t p_elems = (size_t)2 * BATCH * NOUT;         // 16.8M floats =  67 MB
    const size_t need_basic  = (a_elems + b_elems) * sizeof(short);
    const size_t need_splitk = need_basic + p_elems * sizeof(float);

    if (ws_size >= need_basic) {
        short* A_ws = (short*)d_ws;
        short* B_ws = A_ws + a_elems;

        kan_prep_kernel<<<PREP_BLOCKS, 256, 0, stream>>>(x, coef, grid, A_ws, B_ws);

        if (ws_size >= need_splitk) {
            float* P = (float*)(B_ws + b_elems);
            dim3 g2(BATCH / 128, NOUT / 128, 2);             // 1024 blocks = 4/CU
            kan_gemm_splitk<<<g2, 256, 0, stream>>>(A_ws, B_ws, P);
            kan_reduce_kernel<<<1024, 256, 0, stream>>>(P, out);
        } else {
            dim3 g2(BATCH / 128, NOUT / 128);                // 512 blocks = 2/CU
            kan_gemm_kernel<<<g2, 256, 0, stream>>>(A_ws, B_ws, out);
        }
    } else {
        dim3 grd(BATCH / 128, NOUT / 128);
        kan_fused_kernel<<<grd, 256, 0, stream>>>(x, coef, grid, out);
    }
}

// Round 6
// 489.801 us; speedup vs baseline: 3.4340x; 1.0184x over previous
//
#include <hip/hip_runtime.h>
#include <hip/hip_bf16.h>

#define BATCH   4096
#define NIN     2048
#define NOUT    2048
#define GS      8

typedef __attribute__((ext_vector_type(8))) short  bf16x8;   // 8 bf16 = 4 VGPR (MFMA frag)
typedef __attribute__((ext_vector_type(4))) short  bf16x4;   // 8B
typedef __attribute__((ext_vector_type(4))) float  f32x4;

// round-to-nearest-even f32 -> bf16
__device__ __forceinline__ short f2bf(float f) {
    unsigned u = __builtin_bit_cast(unsigned, f);
    u += 0x7fffu + ((u >> 16) & 1u);
    return (short)(u >> 16);
}
__device__ __forceinline__ float bf2f(short s) {
    unsigned u = ((unsigned)(unsigned short)s) << 16;
    return __builtin_bit_cast(float, u);
}

__device__ __forceinline__ bf16x8 basis_bf16(float xv, const float* g) {
    const float KE = -7.2134752044448170f;   // -5 * log2(e)
    float e[GS], s = 0.f;
#pragma unroll
    for (int k = 0; k < GS; ++k) {
        float t = xv - g[k];
        e[k] = __builtin_amdgcn_exp2f(t * t * KE);
        s += e[k];
    }
    float rn = __builtin_amdgcn_rcpf(s + 1e-8f);
    bf16x8 fr;
#pragma unroll
    for (int k = 0; k < GS; ++k) fr[k] = f2bf(e[k] * rn);
    return fr;
}

// async 16B global -> LDS DMA (no VGPR round trip; LDS dest = wave base + lane*16)
__device__ __forceinline__ void async16(const void* g, void* l) {
    __builtin_amdgcn_global_load_lds(
        (const __attribute__((address_space(1))) unsigned*)g,
        (__attribute__((address_space(3))) unsigned*)l, 16, 0, 0);
}

// ======================= PASS 1: prep — cvt and basis CONCURRENT =======================
// Half the blocks stream coef fp32->bf16 (memory-bound), the other half compute
// basis (exp/VALU-heavy) — overlapping the two pipes instead of phase-serializing.
#define PREP_BLOCKS 4096
#define TB 64
#define TI 32

__global__ __launch_bounds__(256, 4)
void kan_prep_kernel(const float* __restrict__ x, const float* __restrict__ coef,
                     const float* __restrict__ grid,
                     short* __restrict__ A_ws, short* __restrict__ B_ws)
{
    __shared__ float tile[TB][TI + 1];
    const int t = threadIdx.x;

    if (blockIdx.x < PREP_BLOCKS / 2) {
        // ---- coef fp32 -> bf16: 8192 chunks of 4096 floats over 2048 blocks.
        // NT loads: coef is read-once -> don't evict A_ws/B_ws from L3.
        for (int c = blockIdx.x; c < (NIN * NOUT * GS) / 4096; c += PREP_BLOCKS / 2) {
            const float* src = coef + (size_t)c * 4096;
            short*       dst = B_ws + (size_t)c * 4096;
            f32x4 v[4];
#pragma unroll
            for (int j = 0; j < 4; ++j)
                v[j] = __builtin_nontemporal_load((const f32x4*)(src + j * 1024 + t * 4));
#pragma unroll
            for (int j = 0; j < 4; ++j) {
                bf16x4 o;
#pragma unroll
                for (int k = 0; k < 4; ++k) o[k] = f2bf(v[j][k]);
                *(bf16x4*)(dst + j * 1024 + t * 4) = o;
            }
        }
        return;
    }

    // ---- basis: 4096 jobs of 64b x 32i tiles (LDS transpose) over 2048 blocks ----
    float g[GS];
#pragma unroll
    for (int k = 0; k < GS; ++k) g[k] = grid[k];

    for (int job = blockIdx.x - PREP_BLOCKS / 2; job < (NIN / TI) * (BATCH / TB);
         job += PREP_BLOCKS / 2) {
        const int i0 = (job & (NIN / TI - 1)) * TI;
        const int b0 = (job / (NIN / TI)) * TB;
        __syncthreads();                             // protect tile from previous job
#pragma unroll
        for (int p = 0; p < (TB * TI) / 256; ++p) {  // reads coalesced over i
            int idx = t + p * 256;
            int b_l = idx >> 5, i_l = idx & 31;
            tile[b_l][i_l] = x[(size_t)(b0 + b_l) * NIN + i0 + i_l];
        }
        __syncthreads();
#pragma unroll
        for (int it = 0; it < 8; ++it) {             // writes coalesced over b
            int b_l = (t & 31) + 32 * (it & 1);
            int i_l = (t >> 5) + 8 * (it >> 1);
            bf16x8 fr = basis_bf16(tile[b_l][i_l], g);
            *(bf16x8*)(A_ws + (size_t)(i0 + i_l) * (BATCH * GS)
                            + (size_t)(b0 + b_l) * GS) = fr;
        }
    }
}

// ============================ PASS 2: GEMM (split-K=2) ============================
// 128x128 tile, 4 waves (2x2 of 64x64). K-step = 8 i's (K=64), LDS DMA.
// 1024 blocks = 4 blocks/CU. Partials stored as bf16 (halves P traffic).
__global__ __launch_bounds__(256, 4)
void kan_gemm_splitk(const short* __restrict__ A_ws, const short* __restrict__ B_ws,
                     short* __restrict__ P)
{
    __shared__ __align__(16) char As[16384];   // 8 i-slices x 128 rows x 16B
    __shared__ __align__(16) char Bs[16384];

    const int t    = threadIdx.x;
    const int wave = t >> 6;
    const int lane = t & 63;
    const int l15  = lane & 15;
    const int quad = lane >> 4;
    const int wm = wave & 1, wn = wave >> 1;
    const int m_blk = blockIdx.x * 128, n_blk = blockIdx.y * 128;
    const int z = blockIdx.z;

    f32x4 acc[4][4];
#pragma unroll
    for (int a = 0; a < 4; ++a)
#pragma unroll
        for (int b = 0; b < 4; ++b)
            acc[a][b] = (f32x4){0.f, 0.f, 0.f, 0.f};

    const char* Abase = (const char*)A_ws + (size_t)m_blk * (GS * 2);
    const char* Bbase = (const char*)B_ws + (size_t)n_blk * (GS * 2);
    const size_t strideA = (size_t)BATCH * GS * 2;   // 64 KB per i
    const size_t strideB = (size_t)NOUT  * GS * 2;   // 32 KB per i

    int dma_off[4], dma_iloc[4], dma_rem[4];
#pragma unroll
    for (int j = 0; j < 4; ++j) {
        dma_off[j]  = j * 4096 + t * 16;
        dma_iloc[j] = dma_off[j] >> 11;
        dma_rem[j]  = dma_off[j] & 2047;
    }

    const int i_lo = z * (NIN / 2), i_hi = i_lo + (NIN / 2);
    for (int i0 = i_lo; i0 < i_hi; i0 += 8) {
#pragma unroll
        for (int j = 0; j < 4; ++j) {
            const size_t i = (size_t)(i0 + dma_iloc[j]);
            async16(Abase + i * strideA + dma_rem[j], As + dma_off[j]);
            async16(Bbase + i * strideB + dma_rem[j], Bs + dma_off[j]);
        }
        __syncthreads();

#pragma unroll
        for (int s = 0; s < 2; ++s) {
            const int iloc = s * 4 + quad;
            bf16x8 af[4], bf[4];
#pragma unroll
            for (int ms = 0; ms < 4; ++ms)
                af[ms] = *(const bf16x8*)(As + (size_t)(iloc * 128 + wm * 64 + ms * 16 + l15) * 16);
#pragma unroll
            for (int ns = 0; ns < 4; ++ns)
                bf[ns] = *(const bf16x8*)(Bs + (size_t)(iloc * 128 + wn * 64 + ns * 16 + l15) * 16);
#pragma unroll
            for (int ms = 0; ms < 4; ++ms)
#pragma unroll
                for (int ns = 0; ns < 4; ++ns)
                    acc[ms][ns] = __builtin_amdgcn_mfma_f32_16x16x32_bf16(
                        af[ms], bf[ns], acc[ms][ns], 0, 0, 0);
        }
        __syncthreads();
    }

    short* Pz = P + (size_t)z * ((size_t)BATCH * NOUT);
    const int m_base = m_blk + wm * 64;
    const int n_base = n_blk + wn * 64;
#pragma unroll
    for (int ms = 0; ms < 4; ++ms)
#pragma unroll
        for (int ns = 0; ns < 4; ++ns) {
            const int col = n_base + ns * 16 + l15;
#pragma unroll
            for (int r = 0; r < 4; ++r) {
                const int row = m_base + ms * 16 + quad * 4 + r;
                Pz[(size_t)row * NOUT + col] = f2bf(acc[ms][ns][r]);
            }
        }
}

// ============================ PASS 3: reduce (bf16 partials) ============================
__global__ __launch_bounds__(256, 4)
void kan_reduce_kernel(const short* __restrict__ P, float* __restrict__ out)
{
    const size_t n8 = (size_t)BATCH * NOUT / 8;     // 1,048,576 groups of 8
    for (size_t idx = (size_t)blockIdx.x * 256 + threadIdx.x; idx < n8;
         idx += (size_t)1024 * 256) {
        bf16x8 a = ((const bf16x8*)P)[idx];
        bf16x8 b = ((const bf16x8*)P)[idx + n8];
        f32x4 o0, o1;
#pragma unroll
        for (int k = 0; k < 4; ++k) {
            o0[k] = bf2f(a[k])     + bf2f(b[k]);
            o1[k] = bf2f(a[k + 4]) + bf2f(b[k + 4]);
        }
        ((f32x4*)out)[idx * 2]     = o0;
        ((f32x4*)out)[idx * 2 + 1] = o1;
    }
}

// ==================== fallback A: single-K GEMM (round-4 proven) ====================
__global__ __launch_bounds__(256, 2)
void kan_gemm_kernel(const short* __restrict__ A_ws, const short* __restrict__ B_ws,
                     float* __restrict__ out)
{
    __shared__ __align__(16) char As[16384];
    __shared__ __align__(16) char Bs[16384];

    const int t    = threadIdx.x;
    const int wave = t >> 6;
    const int lane = t & 63;
    const int l15  = lane & 15;
    const int quad = lane >> 4;
    const int wm = wave & 1, wn = wave >> 1;
    const int m_blk = blockIdx.x * 128, n_blk = blockIdx.y * 128;

    f32x4 acc[4][4];
#pragma unroll
    for (int a = 0; a < 4; ++a)
#pragma unroll
        for (int b = 0; b < 4; ++b)
            acc[a][b] = (f32x4){0.f, 0.f, 0.f, 0.f};

    const char* Abase = (const char*)A_ws + (size_t)m_blk * (GS * 2);
    const char* Bbase = (const char*)B_ws + (size_t)n_blk * (GS * 2);
    const size_t strideA = (size_t)BATCH * GS * 2;
    const size_t strideB = (size_t)NOUT  * GS * 2;

    int dma_off[4], dma_iloc[4], dma_rem[4];
#pragma unroll
    for (int j = 0; j < 4; ++j) {
        dma_off[j]  = j * 4096 + t * 16;
        dma_iloc[j] = dma_off[j] >> 11;
        dma_rem[j]  = dma_off[j] & 2047;
    }

    for (int i0 = 0; i0 < NIN; i0 += 8) {
#pragma unroll
        for (int j = 0; j < 4; ++j) {
            const size_t i = (size_t)(i0 + dma_iloc[j]);
            async16(Abase + i * strideA + dma_rem[j], As + dma_off[j]);
            async16(Bbase + i * strideB + dma_rem[j], Bs + dma_off[j]);
        }
        __syncthreads();
#pragma unroll
        for (int s = 0; s < 2; ++s) {
            const int iloc = s * 4 + quad;
            bf16x8 af[4], bf[4];
#pragma unroll
            for (int ms = 0; ms < 4; ++ms)
                af[ms] = *(const bf16x8*)(As + (size_t)(iloc * 128 + wm * 64 + ms * 16 + l15) * 16);
#pragma unroll
            for (int ns = 0; ns < 4; ++ns)
                bf[ns] = *(const bf16x8*)(Bs + (size_t)(iloc * 128 + wn * 64 + ns * 16 + l15) * 16);
#pragma unroll
            for (int ms = 0; ms < 4; ++ms)
#pragma unroll
                for (int ns = 0; ns < 4; ++ns)
                    acc[ms][ns] = __builtin_amdgcn_mfma_f32_16x16x32_bf16(
                        af[ms], bf[ns], acc[ms][ns], 0, 0, 0);
        }
        __syncthreads();
    }

    const int m_base = m_blk + wm * 64;
    const int n_base = n_blk + wn * 64;
#pragma unroll
    for (int ms = 0; ms < 4; ++ms)
#pragma unroll
        for (int ns = 0; ns < 4; ++ns) {
            const int col = n_base + ns * 16 + l15;
#pragma unroll
            for (int r = 0; r < 4; ++r) {
                const int row = m_base + ms * 16 + quad * 4 + r;
                out[(size_t)row * NOUT + col] = acc[ms][ns][r];
            }
        }
}

// ==================== fallback B: fused (no workspace) ====================
__global__ __launch_bounds__(256, 2)
void kan_fused_kernel(const float* __restrict__ x, const float* __restrict__ coef,
                      const float* __restrict__ grid, float* __restrict__ out)
{
    const int tid  = threadIdx.x;
    const int wave = tid >> 6;
    const int lane = tid & 63;
    const int l15  = lane & 15;
    const int quad = lane >> 4;
    const int m_base = blockIdx.x * 128 + (wave & 1) * 64;
    const int n_base = blockIdx.y * 128 + (wave >> 1) * 64;

    float g[GS];
#pragma unroll
    for (int k = 0; k < GS; ++k) g[k] = grid[k];

    f32x4 acc[4][4];
#pragma unroll
    for (int a = 0; a < 4; ++a)
#pragma unroll
        for (int b = 0; b < 4; ++b) acc[a][b] = (f32x4){0.f, 0.f, 0.f, 0.f};

    const float* xp = x + (size_t)(m_base + l15) * NIN + quad;
    const float* cp = coef + (size_t)quad * (NOUT * GS) + (size_t)(n_base + l15) * GS;

    for (int i0 = 0; i0 < NIN; i0 += 4) {
        f32x4 braw[4][2];
#pragma unroll
        for (int ns = 0; ns < 4; ++ns) {
            const float* p = cp + ns * (16 * GS);
            braw[ns][0] = *(const f32x4*)(p);
            braw[ns][1] = *(const f32x4*)(p + 4);
        }
        bf16x8 afrag[4];
#pragma unroll
        for (int ms = 0; ms < 4; ++ms)
            afrag[ms] = basis_bf16(xp[ms * 16 * NIN], g);
        bf16x8 bfrag[4];
#pragma unroll
        for (int ns = 0; ns < 4; ++ns) {
            bf16x8 fr;
#pragma unroll
            for (int k = 0; k < 4; ++k) { fr[k] = f2bf(braw[ns][0][k]); fr[k+4] = f2bf(braw[ns][1][k]); }
            bfrag[ns] = fr;
        }
#pragma unroll
        for (int ms = 0; ms < 4; ++ms)
#pragma unroll
            for (int ns = 0; ns < 4; ++ns)
                acc[ms][ns] = __builtin_amdgcn_mfma_f32_16x16x32_bf16(
                    afrag[ms], bfrag[ns], acc[ms][ns], 0, 0, 0);
        xp += 4;
        cp += 4 * (NOUT * GS);
    }
#pragma unroll
    for (int ms = 0; ms < 4; ++ms)
#pragma unroll
        for (int ns = 0; ns < 4; ++ns) {
            const int col = n_base + ns * 16 + l15;
#pragma unroll
            for (int r = 0; r < 4; ++r)
                out[(size_t)(m_base + ms * 16 + quad * 4 + r) * NOUT + col] = acc[ms][ns][r];
        }
}

extern "C" void kernel_launch(void* const* d_in, const int* in_sizes, int n_in,
                              void* d_out, int out_size, void* d_ws, size_t ws_size,
                              hipStream_t stream) {
    const float* x    = (const float*)d_in[0];
    const float* coef = (const float*)d_in[1];
    const float* grid = (const float*)d_in[2];
    float* out        = (float*)d_out;

    const size_t a_elems = (size_t)NIN * BATCH * GS;         // 67.1M shorts = 134 MB
    const size_t b_elems = (size_t)NIN * NOUT * GS;          // 33.5M shorts =  67 MB
    const size_t p_elems = (size_t)2 * BATCH * NOUT;         // 16.8M shorts =  33.5 MB
    const size_t need_basic  = (a_elems + b_elems) * sizeof(short);
    const size_t need_splitk = need_basic + p_elems * sizeof(short);

    if (ws_size >= need_basic) {
        short* A_ws = (short*)d_ws;
        short* B_ws = A_ws + a_elems;

        kan_prep_kernel<<<PREP_BLOCKS, 256, 0, stream>>>(x, coef, grid, A_ws, B_ws);

        if (ws_size >= need_splitk) {
            short* P = B_ws + b_elems;
            dim3 g2(BATCH / 128, NOUT / 128, 2);             // 1024 blocks = 4/CU
            kan_gemm_splitk<<<g2, 256, 0, stream>>>(A_ws, B_ws, P);
            kan_reduce_kernel<<<1024, 256, 0, stream>>>(P, out);
        } else {
            dim3 g2(BATCH / 128, NOUT / 128);                // 512 blocks = 2/CU
            kan_gemm_kernel<<<g2, 256, 0, stream>>>(A_ws, B_ws, out);
        }
    } else {
        dim3 grd(BATCH / 128, NOUT / 128);
        kan_fused_kernel<<<grd, 256, 0, stream>>>(x, coef, grid, out);
    }
}